// Round 15
// baseline (279.948 us; speedup 1.0000x reference)
//
#include <hip/hip_runtime.h>

#define HID 32
#define SEQ 512
#define WAVES_PER_BLOCK 8
#define BLOCK (WAVES_PER_BLOCK * 64)

typedef float v2f __attribute__((ext_vector_type(2)));

// ---------------------------------------------------------------------------
// Round-14 structure (240 us best): ONE WAVE = TWO SAMPLES, lane (s,u) owns
// all 4 gates of unit u of sample s; 128 weight floats/lane persistent in
// v96..v223; s_setprio 1 around MAC; 8 h-quads issued up-front with
// descending lgkm waits. Cycle model (validated r12/r14): per wave-step
// issue = 264 MAC + ~160 trans(16cyc ea) + ~64 VALU = 488; 2 waves/SIMD ->
// busy 976 == measured 956. Wall 1125 -> 15% phase-collision idle.
// Round-15 delta (ONE variable): 512-thread blocks, grid 256 = 1 block/CU,
// so waves w and w+4 deterministically share SIMD w%4; the odd group
// (wid>=4) sleeps ~256 cyc ONCE before the loop -> every SIMD pair starts
// in anti-phase (MAC || ACT), zero per-step cost. This is the cheap version
// of round-13's barrier alternation (which paid 78 cyc/step) and the valid
// version of round-10's stagger (which guessed cross-block pairing).
// Per-sample instruction multiset identical to round 14 -> absmax 0.0.
// Register map: q0-3 v64-79, q4-7 v224-239, acc v80-83 (pi,pf | pg,po),
// x v84-85, act temps v86-92, weights (wi,wf)[j]=v[96+2j], (wg,wo)[j]=v[160+2j].
// ---------------------------------------------------------------------------

#define GRP(WA, WB, WC, WD, HP) \
  "v_pk_fma_f32 v[80:81], v[" WA "], " HP ", v[80:81] op_sel_hi:[1,0,1]\n\t" \
  "v_pk_fma_f32 v[82:83], v[" WC "], " HP ", v[82:83] op_sel_hi:[1,0,1]\n\t" \
  "v_pk_fma_f32 v[80:81], v[" WB "], " HP ", v[80:81] op_sel:[0,1,0] op_sel_hi:[1,1,1]\n\t" \
  "v_pk_fma_f32 v[82:83], v[" WD "], " HP ", v[82:83] op_sel:[0,1,0] op_sel_hi:[1,1,1]\n\t"

#define PKIF(E, O, HP) \
  "v_pk_fma_f32 v[80:81], v[" E "], " HP ", v[80:81] op_sel_hi:[1,0,1]\n\t" \
  "v_pk_fma_f32 v[80:81], v[" O "], " HP ", v[80:81] op_sel:[0,1,0] op_sel_hi:[1,1,1]\n\t"
#define PKGO(E, O, HP) \
  "v_pk_fma_f32 v[82:83], v[" E "], " HP ", v[82:83] op_sel_hi:[1,0,1]\n\t" \
  "v_pk_fma_f32 v[82:83], v[" O "], " HP ", v[82:83] op_sel:[0,1,0] op_sel_hi:[1,1,1]\n\t"

// One timestep (byte-identical to round 14).
#define STEP \
  "s_setprio 1\n\t" \
  "ds_read2_b32 v[84:85], %[xa] offset0:0 offset1:0\n\t" \
  "ds_read_b128 v[64:67],   %[hr] offset:0\n\t" \
  "ds_read_b128 v[68:71],   %[hr] offset:16\n\t" \
  "ds_read_b128 v[72:75],   %[hr] offset:32\n\t" \
  "ds_read_b128 v[76:79],   %[hr] offset:48\n\t" \
  "ds_read_b128 v[224:227], %[hr] offset:64\n\t" \
  "ds_read_b128 v[228:231], %[hr] offset:80\n\t" \
  "ds_read_b128 v[232:235], %[hr] offset:96\n\t" \
  "ds_read_b128 v[236:239], %[hr] offset:112\n\t" \
  "v_add_u32 %[xa], 4, %[xa]\n\t" \
  "s_waitcnt lgkmcnt(8)\n\t" \
  "v_pk_fma_f32 v[80:81], %[uvIF], v[84:85], %[bvIF]\n\t" \
  "v_pk_fma_f32 v[82:83], %[uvGO], v[84:85], %[bvGO]\n\t" \
  "s_waitcnt lgkmcnt(7)\n\t" \
  GRP("96:97","98:99","160:161","162:163","v[64:65]") \
  GRP("100:101","102:103","164:165","166:167","v[66:67]") \
  "s_waitcnt lgkmcnt(6)\n\t" \
  GRP("104:105","106:107","168:169","170:171","v[68:69]") \
  GRP("108:109","110:111","172:173","174:175","v[70:71]") \
  "s_waitcnt lgkmcnt(5)\n\t" \
  GRP("112:113","114:115","176:177","178:179","v[72:73]") \
  GRP("116:117","118:119","180:181","182:183","v[74:75]") \
  "s_waitcnt lgkmcnt(4)\n\t" \
  GRP("120:121","122:123","184:185","186:187","v[76:77]") \
  GRP("124:125","126:127","188:189","190:191","v[78:79]") \
  "s_waitcnt lgkmcnt(3)\n\t" \
  GRP("128:129","130:131","192:193","194:195","v[224:225]") \
  GRP("132:133","134:135","196:197","198:199","v[226:227]") \
  "s_waitcnt lgkmcnt(2)\n\t" \
  GRP("136:137","138:139","200:201","202:203","v[228:229]") \
  GRP("140:141","142:143","204:205","206:207","v[230:231]") \
  "s_waitcnt lgkmcnt(1)\n\t" \
  GRP("144:145","146:147","208:209","210:211","v[232:233]") \
  GRP("148:149","150:151","212:213","214:215","v[234:235]") \
  "s_waitcnt lgkmcnt(0)\n\t" \
  PKIF("152:153","154:155","v[236:237]") \
  PKIF("156:157","158:159","v[238:239]") \
  "v_mul_f32 v86, 0xbfb8aa3b, v80\n\t" \
  "v_exp_f32 v86, v86\n\t" \
  "v_mul_f32 v87, 0xbfb8aa3b, v81\n\t" \
  "v_exp_f32 v87, v87\n\t" \
  PKGO("216:217","218:219","v[236:237]") \
  PKGO("220:221","222:223","v[238:239]") \
  "s_setprio 0\n\t" \
  "v_mul_f32 v88, 0x4038aa3b, v82\n\t" \
  "v_exp_f32 v88, v88\n\t" \
  "v_mul_f32 v89, 0xbfb8aa3b, v83\n\t" \
  "v_exp_f32 v89, v89\n\t" \
  "v_add_f32 v86, 1.0, v86\n\t" \
  "v_add_f32 v87, 1.0, v87\n\t" \
  "v_add_f32 v88, 1.0, v88\n\t" \
  "v_add_f32 v89, 1.0, v89\n\t" \
  "v_rcp_f32 v86, v86\n\t" \
  "v_rcp_f32 v87, v87\n\t" \
  "v_rcp_f32 v88, v88\n\t" \
  "v_rcp_f32 v89, v89\n\t" \
  "s_nop 1\n\t" \
  "v_fma_f32 v90, -2.0, v88, 1.0\n\t" \
  "v_mul_f32 v91, v86, v90\n\t" \
  "v_fma_f32 %[c], v87, %[c], v91\n\t" \
  "v_mul_f32 v92, 0x4038aa3b, %[c]\n\t" \
  "v_exp_f32 v92, v92\n\t" \
  "s_nop 1\n\t" \
  "v_add_f32 v92, 1.0, v92\n\t" \
  "v_rcp_f32 v92, v92\n\t" \
  "s_nop 1\n\t" \
  "v_fma_f32 v92, -2.0, v92, 1.0\n\t" \
  "v_mul_f32 %[h], v89, v92\n\t" \
  "ds_write_b32 %[hw], %[h]\n\t"

#define S4  STEP STEP STEP STEP
#define X32 S4 S4 S4 S4 S4 S4 S4 S4

#define CLOBS \
  "v64","v65","v66","v67","v68","v69","v70","v71","v72","v73","v74","v75", \
  "v76","v77","v78","v79","v80","v81","v82","v83","v84","v85","v86","v87", \
  "v88","v89","v90","v91","v92","v93","v94","v95","v96","v97","v98","v99", \
  "v100","v101","v102","v103","v104","v105","v106","v107","v108","v109", \
  "v110","v111","v112","v113","v114","v115","v116","v117","v118","v119", \
  "v120","v121","v122","v123","v124","v125","v126","v127","v128","v129", \
  "v130","v131","v132","v133","v134","v135","v136","v137","v138","v139", \
  "v140","v141","v142","v143","v144","v145","v146","v147","v148","v149", \
  "v150","v151","v152","v153","v154","v155","v156","v157","v158","v159", \
  "v160","v161","v162","v163","v164","v165","v166","v167","v168","v169", \
  "v170","v171","v172","v173","v174","v175","v176","v177","v178","v179", \
  "v180","v181","v182","v183","v184","v185","v186","v187","v188","v189", \
  "v190","v191","v192","v193","v194","v195","v196","v197","v198","v199", \
  "v200","v201","v202","v203","v204","v205","v206","v207","v208","v209", \
  "v210","v211","v212","v213","v214","v215","v216","v217","v218","v219", \
  "v220","v221","v222","v223","v224","v225","v226","v227","v228","v229", \
  "v230","v231","v232","v233","v234","v235","v236","v237","v238","v239"

__global__ __launch_bounds__(BLOCK)
void lstm_fused_kernel(
    const float* __restrict__ x,       // [B, T, 1]
    const float* __restrict__ W_ih,    // [4H, 1]
    const float* __restrict__ W_hh,    // [4H, H] row-major
    const float* __restrict__ b_ih,    // [4H]
    const float* __restrict__ b_hh,    // [4H]
    const float* __restrict__ W_head,  // [1, H]
    const float* __restrict__ b_head,  // [1]
    float* __restrict__ out)           // [B, 1]
{
    __shared__ __align__(16) v2f WIFL[32][34];
    __shared__ __align__(16) v2f WGOL[32][34];
    __shared__ __align__(16) float Xall[WAVES_PER_BLOCK][2][SEQ];   // 32 KB
    __shared__ __align__(16) float Hbuf[WAVES_PER_BLOCK][2][32];

    const int tid = threadIdx.x;
    for (int idx = tid; idx < 1024; idx += BLOCK) {
        const int u = idx >> 5;
        const int j = idx & 31;
        WIFL[u][j] = (v2f){ W_hh[u * 32 + j],        W_hh[(32 + u) * 32 + j] };
        WGOL[u][j] = (v2f){ W_hh[(64 + u) * 32 + j], W_hh[(96 + u) * 32 + j] };
    }
    // Stage all x for this block's 16 samples once (coalesced).
    {
        const int base = blockIdx.x * 16;
        for (int idx = tid; idx < 16 * SEQ; idx += BLOCK) {
            const int smp = idx >> 9;          // 0..15 = wid*2 + s
            const int t   = idx & (SEQ - 1);
            Xall[smp >> 1][smp & 1][t] = x[(size_t)(base + smp) * SEQ + t];
        }
    }
    __syncthreads();

    const int lane = tid & 63;
    const int u    = lane & 31;
    const int s    = lane >> 5;
    const int wid  = tid >> 6;
    const int b0   = blockIdx.x * 16 + wid * 2;

    // Preload weights into persistent v96..v223 (once; every asm block
    // clobbers the range so the compiler never allocates there).
    {
        const unsigned aIF = (unsigned)(size_t)&WIFL[u][0];
        const unsigned aGO = (unsigned)(size_t)&WGOL[u][0];
        asm volatile(
            "ds_read_b128 v[96:99],   %[wa] offset:0\n\t"
            "ds_read_b128 v[100:103], %[wa] offset:16\n\t"
            "ds_read_b128 v[104:107], %[wa] offset:32\n\t"
            "ds_read_b128 v[108:111], %[wa] offset:48\n\t"
            "ds_read_b128 v[112:115], %[wa] offset:64\n\t"
            "ds_read_b128 v[116:119], %[wa] offset:80\n\t"
            "ds_read_b128 v[120:123], %[wa] offset:96\n\t"
            "ds_read_b128 v[124:127], %[wa] offset:112\n\t"
            "ds_read_b128 v[128:131], %[wa] offset:128\n\t"
            "ds_read_b128 v[132:135], %[wa] offset:144\n\t"
            "ds_read_b128 v[136:139], %[wa] offset:160\n\t"
            "ds_read_b128 v[140:143], %[wa] offset:176\n\t"
            "ds_read_b128 v[144:147], %[wa] offset:192\n\t"
            "ds_read_b128 v[148:151], %[wa] offset:208\n\t"
            "ds_read_b128 v[152:155], %[wa] offset:224\n\t"
            "ds_read_b128 v[156:159], %[wa] offset:240\n\t"
            "ds_read_b128 v[160:163], %[wb] offset:0\n\t"
            "ds_read_b128 v[164:167], %[wb] offset:16\n\t"
            "ds_read_b128 v[168:171], %[wb] offset:32\n\t"
            "ds_read_b128 v[172:175], %[wb] offset:48\n\t"
            "ds_read_b128 v[176:179], %[wb] offset:64\n\t"
            "ds_read_b128 v[180:183], %[wb] offset:80\n\t"
            "ds_read_b128 v[184:187], %[wb] offset:96\n\t"
            "ds_read_b128 v[188:191], %[wb] offset:112\n\t"
            "ds_read_b128 v[192:195], %[wb] offset:128\n\t"
            "ds_read_b128 v[196:199], %[wb] offset:144\n\t"
            "ds_read_b128 v[200:203], %[wb] offset:160\n\t"
            "ds_read_b128 v[204:207], %[wb] offset:176\n\t"
            "ds_read_b128 v[208:211], %[wb] offset:192\n\t"
            "ds_read_b128 v[212:215], %[wb] offset:208\n\t"
            "ds_read_b128 v[216:219], %[wb] offset:224\n\t"
            "ds_read_b128 v[220:223], %[wb] offset:240\n\t"
            "s_waitcnt lgkmcnt(0)"
            :
            : [wa]"v"(aIF), [wb]"v"(aGO)
            : "memory", CLOBS);
    }

    const v2f bvIF = { b_ih[u]      + b_hh[u],      b_ih[32 + u] + b_hh[32 + u] };
    const v2f bvGO = { b_ih[64 + u] + b_hh[64 + u], b_ih[96 + u] + b_hh[96 + u] };
    const v2f uvIF = { W_ih[u],      W_ih[32 + u] };
    const v2f uvGO = { W_ih[64 + u], W_ih[96 + u] };

    const unsigned hr = (unsigned)(size_t)&Hbuf[wid][s][0];
    const unsigned hw = hr + (unsigned)(u * 4);
    unsigned xa = (unsigned)(size_t)&Xall[wid][s][0];

    float h = 0.0f, c = 0.0f;
    Hbuf[wid][s][u] = 0.0f;   // h(0); wave-private row, same-wave DS in-order

    // One-time anti-phase stagger: 1 block/CU (grid 256), so waves wid and
    // wid+4 share SIMD wid%4. Odd group sleeps ~256 cyc (~half a step) so
    // each SIMD pair starts MAC||ACT instead of MAC||MAC. Zero per-step cost.
    if (wid >= 4) __builtin_amdgcn_s_sleep(4);

#pragma unroll 1
    for (int t0 = 0; t0 < SEQ; t0 += 32) {
        asm volatile(
            X32
            : [h]"+v"(h), [c]"+v"(c), [xa]"+v"(xa)
            : [hr]"v"(hr), [hw]"v"(hw),
              [uvIF]"v"(uvIF), [bvIF]"v"(bvIF),
              [uvGO]"v"(uvGO), [bvGO]"v"(bvGO)
            : "memory", CLOBS);
    }

    // head: out[b0+s] = sum_u h[u]*W_head[u] + b_head (xor<32 stays per-half)
    float v = h * W_head[u];
#pragma unroll
    for (int off = 16; off >= 1; off >>= 1)
        v += __shfl_xor(v, off);
    if (u == 0) out[b0 + s] = v + b_head[0];
}

extern "C" void kernel_launch(void* const* d_in, const int* in_sizes, int n_in,
                              void* d_out, int out_size, void* d_ws, size_t ws_size,
                              hipStream_t stream) {
    const float* x      = (const float*)d_in[0];
    const float* W_ih   = (const float*)d_in[1];
    const float* W_hh   = (const float*)d_in[2];
    const float* b_ih   = (const float*)d_in[3];
    const float* b_hh   = (const float*)d_in[4];
    const float* W_head = (const float*)d_in[5];
    const float* b_head = (const float*)d_in[6];
    float* out = (float*)d_out;

    const int B = in_sizes[0] / SEQ;            // 4096
    const int grid = B / 16;                    // 256 blocks = 1/CU, 8 waves

    lstm_fused_kernel<<<grid, BLOCK, 0, stream>>>(
        x, W_ih, W_hh, b_ih, b_hh, W_head, b_head, out);
}